// Round 1
// baseline (452.046 us; speedup 1.0000x reference)
//
#include <hip/hip_runtime.h>

// LSTMCell with attention, MI355X gfx950.
// gates = X@Wih^T + b_ih + Hx@Whh^T + b_hh ; att_gates = Att@Watt^T + b_att
// cy = sig(f)*cx + sig(i)*tanh(g) + sig(i_att)*tanh(a_att); hy = sig(o)*tanh(cy)
//
// Plan: bf16 MFMA (16x16x32), m97-style tiles (128 rows x 128 cols, BK=32,
// global_load_lds width 16, 2-barrier K-loop), fused epilogues.

typedef __attribute__((ext_vector_type(8))) __bf16 bf16x8;
typedef __attribute__((ext_vector_type(8))) unsigned short ushort8;
typedef __attribute__((ext_vector_type(4))) float f32x4;

#define AS1 __attribute__((address_space(1)))
#define AS3 __attribute__((address_space(3)))

__device__ __forceinline__ void gld16(const unsigned short* g, unsigned short* l) {
    __builtin_amdgcn_global_load_lds((const AS1 void*)g, (AS3 void*)l, 16, 0, 0);
}

__device__ __forceinline__ unsigned short f2bf(float f) {
    unsigned int u = __builtin_bit_cast(unsigned int, f);
    u += 0x7fffu + ((u >> 16) & 1u);   // RNE
    return (unsigned short)(u >> 16);
}

__device__ __forceinline__ float sigmoidf_(float x) { return 1.f / (1.f + __expf(-x)); }
__device__ __forceinline__ float tanhf_(float x) {
    float e = __expf(-2.f * fabsf(x));
    float t = (1.f - e) / (1.f + e);
    return x >= 0.f ? t : -t;
}

__device__ __forceinline__ bf16x8 ldfrag(const unsigned short* p) {
    return __builtin_bit_cast(bf16x8, *(const ushort8*)p);
}

// ---------------- cast/pack kernels ----------------
// src is row-major [rows x 1024] fp32; dst row-major with leading dim dst_ld,
// column offset dst_off. 4 elements per thread.
__global__ void cast_bf16_k(unsigned short* __restrict__ dst, const float* __restrict__ src,
                            int n4, int dst_ld, int dst_off) {
    int i = blockIdx.x * blockDim.x + threadIdx.x;
    if (i >= n4) return;
    int e = i * 4;
    int r = e >> 10;       // src cols == 1024 always
    int c = e & 1023;
    const float4 v = *(const float4*)(src + e);
    ushort4 p;
    p.x = f2bf(v.x); p.y = f2bf(v.y); p.z = f2bf(v.z); p.w = f2bf(v.w);
    *(ushort4*)(dst + r * dst_ld + dst_off + c) = p;
}

__global__ void bias_sum_k(float* __restrict__ dst, const float* __restrict__ a,
                           const float* __restrict__ b, int n) {
    int i = blockIdx.x * blockDim.x + threadIdx.x;
    if (i < n) dst[i] = a[i] + b[i];
}

// ---------------- attention GEMM (fused sigmoid*tanh) ----------------
// C = ATT[8192x1024] @ WA[2048x1024]^T. Block: 128 rows x (2 slices x 64 cols).
// Slice 0 = weight rows n0..n0+63 (ingate_att), slice 1 = 1024+n0.. (attgate).
// attprod[r, n0+j] = sigmoid(c0 + b_att[j']) * tanh(c1 + b_att[1024+j'])
__global__ __launch_bounds__(256, 2) void att_gemm_k(
    const unsigned short* __restrict__ ATT, const unsigned short* __restrict__ WA,
    const float* __restrict__ bias_att, float* __restrict__ attprod)
{
    __shared__ unsigned short As[128 * 32];
    __shared__ unsigned short Bs[128 * 32];
    const int tid  = threadIdx.x;
    const int wave = tid >> 6, lane = tid & 63;
    const int l15 = lane & 15, quad = lane >> 4;
    const int row0 = blockIdx.x * 128;
    const int n0   = blockIdx.y * 64;

    f32x4 acc[2][8];
    const f32x4 z = {0.f, 0.f, 0.f, 0.f};
#pragma unroll
    for (int i = 0; i < 2; ++i)
#pragma unroll
        for (int j = 0; j < 8; ++j) acc[i][j] = z;

    // staging: 512 chunks of 16B per tile; thread t does chunks t and t+256.
    const int ar = tid >> 2, kp = tid & 3;          // row 0..63, k-part 0..3
    const unsigned short* aG0 = ATT + (row0 + ar) * 1024 + kp * 8;
    const unsigned short* aG1 = aG0 + 64 * 1024;
    const unsigned short* bG0 = WA + (n0 + ar) * 1024 + kp * 8;          // slice 0
    const unsigned short* bG1 = WA + (1024 + n0 + ar) * 1024 + kp * 8;   // slice 1
    unsigned short* aL0 = As + tid * 8;  unsigned short* aL1 = As + (tid + 256) * 8;
    unsigned short* bL0 = Bs + tid * 8;  unsigned short* bL1 = Bs + (tid + 256) * 8;

    const int aoff0 = (wave * 32 + l15) * 32 + quad * 8;
    const int aoff1 = aoff0 + 16 * 32;

    for (int kt = 0; kt < 32; ++kt) {
        gld16(aG0, aL0); gld16(aG1, aL1);
        gld16(bG0, bL0); gld16(bG1, bL1);
        aG0 += 32; aG1 += 32; bG0 += 32; bG1 += 32;
        __syncthreads();                     // waits vmcnt(0): DMA landed
        bf16x8 a0 = ldfrag(As + aoff0);
        bf16x8 a1 = ldfrag(As + aoff1);
#pragma unroll
        for (int cf = 0; cf < 8; ++cf) {
            bf16x8 b = ldfrag(Bs + (cf * 16 + l15) * 32 + quad * 8);
            acc[0][cf] = __builtin_amdgcn_mfma_f32_16x16x32_bf16(a0, b, acc[0][cf], 0, 0, 0);
            acc[1][cf] = __builtin_amdgcn_mfma_f32_16x16x32_bf16(a1, b, acc[1][cf], 0, 0, 0);
        }
        __syncthreads();                     // reads done before next overwrite
    }

    const int Rbase = row0 + wave * 32 + quad * 4;
#pragma unroll
    for (int rf = 0; rf < 2; ++rf)
#pragma unroll
        for (int jf = 0; jf < 4; ++jf) {
            int col = n0 + jf * 16 + l15;
            float b0 = bias_att[col], b1 = bias_att[1024 + col];
#pragma unroll
            for (int reg = 0; reg < 4; ++reg) {
                int R = Rbase + rf * 16 + reg;
                float ia = sigmoidf_(acc[rf][jf][reg] + b0);
                float ag = tanhf_(acc[rf][4 + jf][reg] + b1);
                attprod[R * 1024 + col] = ia * ag;
            }
        }
}

// ---------------- main GEMM (fused LSTM epilogue) ----------------
// C = XH[8192x2048] @ W4[4096x2048]^T, block cols = 4 gates x 32 H-cols.
// Wave grid 4x1: each wave 32 rows x 128 cols -> i,f,g,o for a (row,col) all
// land in the same lane/reg -> in-register epilogue.
__global__ __launch_bounds__(256, 2) void main_gemm_k(
    const unsigned short* __restrict__ XH, const unsigned short* __restrict__ W4,
    const float* __restrict__ bias4, const float* __restrict__ attprod,
    const float* __restrict__ cx, float* __restrict__ out)
{
    __shared__ unsigned short As[128 * 32];
    __shared__ unsigned short Bs[128 * 32];
    const int tid  = threadIdx.x;
    const int wave = tid >> 6, lane = tid & 63;
    const int l15 = lane & 15, quad = lane >> 4;
    const int row0 = blockIdx.x * 128;   // 64 blocks
    const int n0   = blockIdx.y * 32;    // 32 blocks of 32 H-cols

    f32x4 acc[2][8];
    const f32x4 z = {0.f, 0.f, 0.f, 0.f};
#pragma unroll
    for (int i = 0; i < 2; ++i)
#pragma unroll
        for (int j = 0; j < 8; ++j) acc[i][j] = z;

    const int ar = tid >> 2, kp = tid & 3;
    const unsigned short* aG0 = XH + (row0 + ar) * 2048 + kp * 8;
    const unsigned short* aG1 = aG0 + 64 * 2048;
    // B tile rows rr = gate*32 + j  ->  global weight row gate*1024 + n0 + j
    const unsigned short* bG0 = W4 + ((ar >> 5) * 1024 + n0 + (ar & 31)) * 2048 + kp * 8;
    const unsigned short* bG1 = bG0 + 2 * 1024 * 2048;   // rows +64 => gate +2
    unsigned short* aL0 = As + tid * 8;  unsigned short* aL1 = As + (tid + 256) * 8;
    unsigned short* bL0 = Bs + tid * 8;  unsigned short* bL1 = Bs + (tid + 256) * 8;

    const int aoff0 = (wave * 32 + l15) * 32 + quad * 8;
    const int aoff1 = aoff0 + 16 * 32;

    for (int kt = 0; kt < 64; ++kt) {
        gld16(aG0, aL0); gld16(aG1, aL1);
        gld16(bG0, bL0); gld16(bG1, bL1);
        aG0 += 32; aG1 += 32; bG0 += 32; bG1 += 32;
        __syncthreads();
        bf16x8 a0 = ldfrag(As + aoff0);
        bf16x8 a1 = ldfrag(As + aoff1);
#pragma unroll
        for (int cf = 0; cf < 8; ++cf) {
            bf16x8 b = ldfrag(Bs + (cf * 16 + l15) * 32 + quad * 8);
            acc[0][cf] = __builtin_amdgcn_mfma_f32_16x16x32_bf16(a0, b, acc[0][cf], 0, 0, 0);
            acc[1][cf] = __builtin_amdgcn_mfma_f32_16x16x32_bf16(a1, b, acc[1][cf], 0, 0, 0);
        }
        __syncthreads();
    }

    // epilogue: col frag cf = gate*2 + jp (jp selects 16-col half of the 32)
    const int Rbase = row0 + wave * 32 + quad * 4;
    const int CYOFF = 8192 * 1024;
#pragma unroll
    for (int rf = 0; rf < 2; ++rf)
#pragma unroll
        for (int jp = 0; jp < 2; ++jp) {
            int col = n0 + jp * 16 + l15;
            float bi = bias4[col];
            float bff = bias4[1024 + col];
            float bg = bias4[2048 + col];
            float bo = bias4[3072 + col];
#pragma unroll
            for (int reg = 0; reg < 4; ++reg) {
                int R = Rbase + rf * 16 + reg;
                int off = R * 1024 + col;
                float ig = sigmoidf_(acc[rf][0 + jp][reg] + bi);
                float fg = sigmoidf_(acc[rf][2 + jp][reg] + bff);
                float gg = tanhf_(acc[rf][4 + jp][reg] + bg);
                float og = sigmoidf_(acc[rf][6 + jp][reg] + bo);
                float cyv = fg * cx[off] + ig * gg + attprod[off];
                float hyv = og * tanhf_(cyv);
                out[off] = hyv;
                out[CYOFF + off] = cyv;
            }
        }
}

// ---------------- launch ----------------
extern "C" void kernel_launch(void* const* d_in, const int* in_sizes, int n_in,
                              void* d_out, int out_size, void* d_ws, size_t ws_size,
                              hipStream_t stream) {
    const float* input = (const float*)d_in[0];
    const float* hx    = (const float*)d_in[1];
    const float* cx    = (const float*)d_in[2];
    const float* att   = (const float*)d_in[3];
    const float* w_ih  = (const float*)d_in[4];
    const float* w_hh  = (const float*)d_in[5];
    const float* b_ih  = (const float*)d_in[6];
    const float* b_hh  = (const float*)d_in[7];
    const float* w_att = (const float*)d_in[8];
    const float* b_att = (const float*)d_in[9];
    float* out = (float*)d_out;

    char* ws = (char*)d_ws;
    unsigned short* XH   = (unsigned short*)(ws);                    // 8192x2048 bf16 (32MB)
    unsigned short* ATTb = (unsigned short*)(ws + 33554432);         // 8192x1024 bf16 (16MB)
    unsigned short* W4   = (unsigned short*)(ws + 50331648);         // 4096x2048 bf16 (16MB)
    unsigned short* WA   = (unsigned short*)(ws + 67108864);         // 2048x1024 bf16 (4MB)
    float* bias4         = (float*)(ws + 71303168);                  // 4096 f32
    float* attprod       = (float*)(ws + 71319552);                  // 8192x1024 f32 (32MB)

    const int blk = 256;
    auto g4 = [](int n) { return (n / 4 + 255) / 256; };
    cast_bf16_k<<<g4(8192 * 1024), blk, 0, stream>>>(XH, input, 8192 * 1024 / 4, 2048, 0);
    cast_bf16_k<<<g4(8192 * 1024), blk, 0, stream>>>(XH, hx,    8192 * 1024 / 4, 2048, 1024);
    cast_bf16_k<<<g4(8192 * 1024), blk, 0, stream>>>(ATTb, att, 8192 * 1024 / 4, 1024, 0);
    cast_bf16_k<<<g4(4096 * 1024), blk, 0, stream>>>(W4, w_ih,  4096 * 1024 / 4, 2048, 0);
    cast_bf16_k<<<g4(4096 * 1024), blk, 0, stream>>>(W4, w_hh,  4096 * 1024 / 4, 2048, 1024);
    cast_bf16_k<<<g4(2048 * 1024), blk, 0, stream>>>(WA, w_att, 2048 * 1024 / 4, 1024, 0);
    bias_sum_k<<<16, 256, 0, stream>>>(bias4, b_ih, b_hh, 4096);

    att_gemm_k<<<dim3(64, 16), 256, 0, stream>>>(ATTb, WA, b_att, attprod);
    main_gemm_k<<<dim3(64, 32), 256, 0, stream>>>(XH, W4, bias4, attprod, cx, out);
}

// Round 2
// 437.573 us; speedup vs baseline: 1.0331x; 1.0331x over previous
//
#include <hip/hip_runtime.h>

// LSTMCell with attention, MI355X gfx950.
// Round 2: (1) XOR-swizzled LDS chunk layout to kill 8-way bank conflicts on
// ds_read_b128 fragment reads (2.1e7 conflict cycles/dispatch in round 1);
// (2) all casts + bias fused into one kernel (was 7 launches).

typedef __attribute__((ext_vector_type(8))) __bf16 bf16x8;
typedef __attribute__((ext_vector_type(8))) unsigned short ushort8;
typedef __attribute__((ext_vector_type(4))) float f32x4;

#define AS1 __attribute__((address_space(1)))
#define AS3 __attribute__((address_space(3)))

__device__ __forceinline__ void gld16(const unsigned short* g, unsigned short* l) {
    __builtin_amdgcn_global_load_lds((const AS1 void*)g, (AS3 void*)l, 16, 0, 0);
}

__device__ __forceinline__ unsigned short f2bf(float f) {
    unsigned int u = __builtin_bit_cast(unsigned int, f);
    u += 0x7fffu + ((u >> 16) & 1u);   // RNE
    return (unsigned short)(u >> 16);
}

__device__ __forceinline__ float sigmoidf_(float x) { return 1.f / (1.f + __expf(-x)); }
__device__ __forceinline__ float tanhf_(float x) {
    float e = __expf(-2.f * fabsf(x));
    float t = (1.f - e) / (1.f + e);
    return x >= 0.f ? t : -t;
}

__device__ __forceinline__ bf16x8 ldfrag(const unsigned short* p) {
    return __builtin_bit_cast(bf16x8, *(const ushort8*)p);
}

// ---------------- fused cast/pack + bias kernel ----------------
// Segments (float4 units): input->XH[:,0:1024], hx->XH[:,1024:2048],
// att->ATTb, w_ih->W4[:,0:1024], w_hh->W4[:,1024:2048], w_att->WA.
__global__ void cast_all_k(const float* __restrict__ input, const float* __restrict__ hx,
                           const float* __restrict__ att,   const float* __restrict__ w_ih,
                           const float* __restrict__ w_hh,  const float* __restrict__ w_att,
                           const float* __restrict__ b_ih,  const float* __restrict__ b_hh,
                           unsigned short* __restrict__ XH, unsigned short* __restrict__ ATTb,
                           unsigned short* __restrict__ W4, unsigned short* __restrict__ WA,
                           float* __restrict__ bias4)
{
    int gid = blockIdx.x * blockDim.x + threadIdx.x;
    if (gid < 4096) bias4[gid] = b_ih[gid] + b_hh[gid];
    const int total = 8912896;  // sum of all segment sizes in float4s
    for (int i = gid; i < total; i += gridDim.x * blockDim.x) {
        const float* src; unsigned short* dst; int ld, off, rel;
        if (i < 2097152)      { src = input; dst = XH;   ld = 2048; off = 0;    rel = i; }
        else if (i < 4194304) { src = hx;    dst = XH;   ld = 2048; off = 1024; rel = i - 2097152; }
        else if (i < 6291456) { src = att;   dst = ATTb; ld = 1024; off = 0;    rel = i - 4194304; }
        else if (i < 7340032) { src = w_ih;  dst = W4;   ld = 2048; off = 0;    rel = i - 6291456; }
        else if (i < 8388608) { src = w_hh;  dst = W4;   ld = 2048; off = 1024; rel = i - 7340032; }
        else                  { src = w_att; dst = WA;   ld = 1024; off = 0;    rel = i - 8388608; }
        int e = rel * 4;
        int r = e >> 10, c = e & 1023;   // all sources have 1024 fp32 cols
        const float4 v = *(const float4*)(src + e);
        ushort4 p;
        p.x = f2bf(v.x); p.y = f2bf(v.y); p.z = f2bf(v.z); p.w = f2bf(v.w);
        *(ushort4*)(dst + r * ld + off + c) = p;
    }
}

// ---------------- attention GEMM (fused sigmoid*tanh) ----------------
// C = ATT[8192x1024] @ WA[2048x1024]^T. Block: 128 rows x (2 slices x 64 cols).
// attprod[r, n0+j] = sigmoid(c0 + b_att[j']) * tanh(c1 + b_att[1024+j'])
__global__ __launch_bounds__(256, 2) void att_gemm_k(
    const unsigned short* __restrict__ ATT, const unsigned short* __restrict__ WA,
    const float* __restrict__ bias_att, float* __restrict__ attprod)
{
    __shared__ unsigned short As[128 * 32];
    __shared__ unsigned short Bs[128 * 32];
    const int tid  = threadIdx.x;
    const int wave = tid >> 6, lane = tid & 63;
    const int l15 = lane & 15, quad = lane >> 4;
    const int row0 = blockIdx.x * 128;
    const int n0   = blockIdx.y * 64;

    f32x4 acc[2][8];
    const f32x4 z = {0.f, 0.f, 0.f, 0.f};
#pragma unroll
    for (int i = 0; i < 2; ++i)
#pragma unroll
        for (int j = 0; j < 8; ++j) acc[i][j] = z;

    // Staging: thread t owns LDS chunk t (and t+256); global k-chunk is
    // XOR-swizzled so fragment reads are 2-way-conflict-free.
    const int ar = tid >> 2;
    const int kp_sw = (tid & 3) ^ ((ar >> 1) & 3);
    const unsigned short* aG0 = ATT + (row0 + ar) * 1024 + kp_sw * 8;
    const unsigned short* aG1 = aG0 + 64 * 1024;
    const unsigned short* bG0 = WA + (n0 + ar) * 1024 + kp_sw * 8;          // slice 0
    const unsigned short* bG1 = WA + (1024 + n0 + ar) * 1024 + kp_sw * 8;   // slice 1
    unsigned short* aL0 = As + tid * 8;  unsigned short* aL1 = As + (tid + 256) * 8;
    unsigned short* bL0 = Bs + tid * 8;  unsigned short* bL1 = Bs + (tid + 256) * 8;

    // Fragment read swizzle term — lane-constant, loop-invariant.
    const int sw8 = (quad ^ ((l15 >> 1) & 3)) * 8;
    const int aoff0 = (wave * 32 + l15) * 32 + sw8;
    const int aoff1 = aoff0 + 16 * 32;

    for (int kt = 0; kt < 32; ++kt) {
        gld16(aG0, aL0); gld16(aG1, aL1);
        gld16(bG0, bL0); gld16(bG1, bL1);
        aG0 += 32; aG1 += 32; bG0 += 32; bG1 += 32;
        __syncthreads();
        bf16x8 a0 = ldfrag(As + aoff0);
        bf16x8 a1 = ldfrag(As + aoff1);
#pragma unroll
        for (int cf = 0; cf < 8; ++cf) {
            bf16x8 b = ldfrag(Bs + (cf * 16 + l15) * 32 + sw8);
            acc[0][cf] = __builtin_amdgcn_mfma_f32_16x16x32_bf16(a0, b, acc[0][cf], 0, 0, 0);
            acc[1][cf] = __builtin_amdgcn_mfma_f32_16x16x32_bf16(a1, b, acc[1][cf], 0, 0, 0);
        }
        __syncthreads();
    }

    const int Rbase = row0 + wave * 32 + quad * 4;
#pragma unroll
    for (int rf = 0; rf < 2; ++rf)
#pragma unroll
        for (int jf = 0; jf < 4; ++jf) {
            int col = n0 + jf * 16 + l15;
            float b0 = bias_att[col], b1 = bias_att[1024 + col];
#pragma unroll
            for (int reg = 0; reg < 4; ++reg) {
                int R = Rbase + rf * 16 + reg;
                float ia = sigmoidf_(acc[rf][jf][reg] + b0);
                float ag = tanhf_(acc[rf][4 + jf][reg] + b1);
                attprod[R * 1024 + col] = ia * ag;
            }
        }
}

// ---------------- main GEMM (fused LSTM epilogue) ----------------
// C = XH[8192x2048] @ W4[4096x2048]^T, block cols = 4 gates x 32 H-cols ->
// i,f,g,o for a (row,col) land in the same lane/reg -> in-register epilogue.
__global__ __launch_bounds__(256, 2) void main_gemm_k(
    const unsigned short* __restrict__ XH, const unsigned short* __restrict__ W4,
    const float* __restrict__ bias4, const float* __restrict__ attprod,
    const float* __restrict__ cx, float* __restrict__ out)
{
    __shared__ unsigned short As[128 * 32];
    __shared__ unsigned short Bs[128 * 32];
    const int tid  = threadIdx.x;
    const int wave = tid >> 6, lane = tid & 63;
    const int l15 = lane & 15, quad = lane >> 4;
    const int row0 = blockIdx.x * 128;   // 64 blocks
    const int n0   = blockIdx.y * 32;    // 32 blocks of 32 H-cols

    f32x4 acc[2][8];
    const f32x4 z = {0.f, 0.f, 0.f, 0.f};
#pragma unroll
    for (int i = 0; i < 2; ++i)
#pragma unroll
        for (int j = 0; j < 8; ++j) acc[i][j] = z;

    const int ar = tid >> 2;
    const int kp_sw = (tid & 3) ^ ((ar >> 1) & 3);
    const unsigned short* aG0 = XH + (row0 + ar) * 2048 + kp_sw * 8;
    const unsigned short* aG1 = aG0 + 64 * 2048;
    // B tile row rr = gate*32 + j  ->  global weight row gate*1024 + n0 + j
    const unsigned short* bG0 = W4 + ((ar >> 5) * 1024 + n0 + (ar & 31)) * 2048 + kp_sw * 8;
    const unsigned short* bG1 = bG0 + 2 * 1024 * 2048;   // tile rows +64 => gate +2
    unsigned short* aL0 = As + tid * 8;  unsigned short* aL1 = As + (tid + 256) * 8;
    unsigned short* bL0 = Bs + tid * 8;  unsigned short* bL1 = Bs + (tid + 256) * 8;

    const int sw8 = (quad ^ ((l15 >> 1) & 3)) * 8;
    const int aoff0 = (wave * 32 + l15) * 32 + sw8;
    const int aoff1 = aoff0 + 16 * 32;

    for (int kt = 0; kt < 64; ++kt) {
        gld16(aG0, aL0); gld16(aG1, aL1);
        gld16(bG0, bL0); gld16(bG1, bL1);
        aG0 += 32; aG1 += 32; bG0 += 32; bG1 += 32;
        __syncthreads();
        bf16x8 a0 = ldfrag(As + aoff0);
        bf16x8 a1 = ldfrag(As + aoff1);
#pragma unroll
        for (int cf = 0; cf < 8; ++cf) {
            bf16x8 b = ldfrag(Bs + (cf * 16 + l15) * 32 + sw8);
            acc[0][cf] = __builtin_amdgcn_mfma_f32_16x16x32_bf16(a0, b, acc[0][cf], 0, 0, 0);
            acc[1][cf] = __builtin_amdgcn_mfma_f32_16x16x32_bf16(a1, b, acc[1][cf], 0, 0, 0);
        }
        __syncthreads();
    }

    // epilogue: col frag cf = gate*2 + jp (jp selects 16-col half of the 32)
    const int Rbase = row0 + wave * 32 + quad * 4;
    const int CYOFF = 8192 * 1024;
#pragma unroll
    for (int rf = 0; rf < 2; ++rf)
#pragma unroll
        for (int jp = 0; jp < 2; ++jp) {
            int col = n0 + jp * 16 + l15;
            float bi  = bias4[col];
            float bff = bias4[1024 + col];
            float bg  = bias4[2048 + col];
            float bo  = bias4[3072 + col];
#pragma unroll
            for (int reg = 0; reg < 4; ++reg) {
                int R = Rbase + rf * 16 + reg;
                int off = R * 1024 + col;
                float ig = sigmoidf_(acc[rf][0 + jp][reg] + bi);
                float fg = sigmoidf_(acc[rf][2 + jp][reg] + bff);
                float gg = tanhf_(acc[rf][4 + jp][reg] + bg);
                float og = sigmoidf_(acc[rf][6 + jp][reg] + bo);
                float cyv = fg * cx[off] + ig * gg + attprod[off];
                float hyv = og * tanhf_(cyv);
                out[off] = hyv;
                out[CYOFF + off] = cyv;
            }
        }
}

// ---------------- launch ----------------
extern "C" void kernel_launch(void* const* d_in, const int* in_sizes, int n_in,
                              void* d_out, int out_size, void* d_ws, size_t ws_size,
                              hipStream_t stream) {
    const float* input = (const float*)d_in[0];
    const float* hx    = (const float*)d_in[1];
    const float* cx    = (const float*)d_in[2];
    const float* att   = (const float*)d_in[3];
    const float* w_ih  = (const float*)d_in[4];
    const float* w_hh  = (const float*)d_in[5];
    const float* b_ih  = (const float*)d_in[6];
    const float* b_hh  = (const float*)d_in[7];
    const float* w_att = (const float*)d_in[8];
    const float* b_att = (const float*)d_in[9];
    float* out = (float*)d_out;

    char* ws = (char*)d_ws;
    unsigned short* XH   = (unsigned short*)(ws);                    // 8192x2048 bf16 (32MB)
    unsigned short* ATTb = (unsigned short*)(ws + 33554432);         // 8192x1024 bf16 (16MB)
    unsigned short* W4   = (unsigned short*)(ws + 50331648);         // 4096x2048 bf16 (16MB)
    unsigned short* WA   = (unsigned short*)(ws + 67108864);         // 2048x1024 bf16 (4MB)
    float* bias4         = (float*)(ws + 71303168);                  // 4096 f32
    float* attprod       = (float*)(ws + 71319552);                  // 8192x1024 f32 (32MB)

    cast_all_k<<<34816, 256, 0, stream>>>(input, hx, att, w_ih, w_hh, w_att,
                                          b_ih, b_hh, XH, ATTb, W4, WA, bias4);
    att_gemm_k<<<dim3(64, 16), 256, 0, stream>>>(ATTb, WA, b_att, attprod);
    main_gemm_k<<<dim3(64, 32), 256, 0, stream>>>(XH, W4, bias4, attprod, cx, out);
}